// Round 3
// baseline (811.945 us; speedup 1.0000x reference)
//
#include <hip/hip_runtime.h>
#include <stdint.h>

#define B_ 4
#define C_ 256
#define N_ 4096
#define TK 32

using floatx4 = __attribute__((ext_vector_type(4))) float;
using halfx8  = __attribute__((ext_vector_type(8))) _Float16;

__device__ __forceinline__ float bf16_to_f(uint16_t u) {
    union { uint32_t u; float f; } c; c.u = ((uint32_t)u) << 16; return c.f;
}
__device__ __forceinline__ uint16_t f_to_bf16(float f) {
    union { float f; uint32_t u; } c; c.f = f;
    uint32_t u = c.u;
    u += 0x7FFFu + ((u >> 16) & 1u);   // RNE
    return (uint16_t)(u >> 16);
}

// ---------------- sniff input dtype (1 = f32, 0 = bf16) ----------------
__global__ void sniff_kernel(const uint16_t* __restrict__ wq_u16, int* __restrict__ flag) {
    __shared__ int cnt;
    if (threadIdx.x == 0) cnt = 0;
    __syncthreads();
    int local = 0;
    for (int i = threadIdx.x; i < 8192; i += 256) {
        int e = (wq_u16[i] >> 7) & 0xFF;
        if (e >= 132) local++;
    }
    atomicAdd(&cnt, local);
    __syncthreads();
    if (threadIdx.x == 0) *flag = (cnt > 64) ? 1 : 0;
}

// ---------------- W -> f16 ----------------
__global__ void wconv_kernel(const void* __restrict__ wq,
                             const void* __restrict__ wk,
                             const void* __restrict__ wv,
                             _Float16* __restrict__ wf,
                             const int* __restrict__ flag) {
    const int isf32 = *flag;
    int idx = blockIdx.x * 256 + threadIdx.x;
    int mat = idx >> 16;
    int off = idx & 65535;
    const void* src = (mat == 0) ? wq : ((mat == 1) ? wk : wv);
    float v = isf32 ? ((const float*)src)[off] : bf16_to_f(((const uint16_t*)src)[off]);
    wf[idx] = (_Float16)v;
}

// ---------------- QKV projection (MFMA f16), mat = blockIdx.z ----------------
__global__ __launch_bounds__(256) void proj_kernel(
    const void* __restrict__ x_raw,      // (B,C,N) bf16 or f32
    const _Float16* __restrict__ wf,     // 3 x (C,C) f16
    _Float16* __restrict__ qt,           // (B,N,C)
    _Float16* __restrict__ kt,           // (B,N,C)
    _Float16* __restrict__ v,            // (B,C,N)
    const int* __restrict__ flag) {
    const int isf32 = *flag;
    const int b = blockIdx.y;
    const int mat = blockIdx.z;
    const int n0 = blockIdx.x * 64;
    const int tid = threadIdx.x;
    const int w = tid >> 6;
    const int L = tid & 63;
    const int lane15 = L & 15;
    const int quad = L >> 4;
    const int n = n0 + w * 16 + lane15;

    // B-frags: B[k=c][n], lane holds c = cs*32 + quad*8 + j
    halfx8 bfrag[8];
    const size_t xbase = (size_t)b * C_ * N_;
    if (isf32) {
        const float* xb = (const float*)x_raw + xbase;
#pragma unroll
        for (int cs = 0; cs < 8; ++cs) {
            const int cbase = cs * 32 + quad * 8;
            halfx8 f;
#pragma unroll
            for (int j = 0; j < 8; ++j)
                f[j] = (_Float16)xb[(size_t)(cbase + j) * N_ + n];
            bfrag[cs] = f;
        }
    } else {
        const uint16_t* xb = (const uint16_t*)x_raw + xbase;
#pragma unroll
        for (int cs = 0; cs < 8; ++cs) {
            const int cbase = cs * 32 + quad * 8;
            halfx8 f;
#pragma unroll
            for (int j = 0; j < 8; ++j)
                f[j] = (_Float16)bf16_to_f(xb[(size_t)(cbase + j) * N_ + n]);
            bfrag[cs] = f;
        }
    }

    const _Float16* wm = wf + mat * (C_ * C_);
#pragma unroll 4
    for (int ot = 0; ot < 16; ++ot) {
        const int obase = ot * 16;
        floatx4 acc = {0.f, 0.f, 0.f, 0.f};
        const _Float16* wrow = wm + (size_t)(obase + lane15) * C_ + quad * 8;
#pragma unroll
        for (int cs = 0; cs < 8; ++cs) {
            halfx8 af = *(const halfx8*)(wrow + cs * 32);
            acc = __builtin_amdgcn_mfma_f32_16x16x32_f16(af, bfrag[cs], acc, 0, 0, 0);
        }
        // D[o][n]: col n = lane15, row o = obase + quad*4 + r
        if (mat < 2) {
            _Float16* dst = (mat == 0 ? qt : kt) +
                            ((size_t)b * N_ + n) * C_ + obase + quad * 4;
            union { _Float16 h[4]; unsigned long long u64; } pk;
#pragma unroll
            for (int r = 0; r < 4; ++r) pk.h[r] = (_Float16)acc[r];
            *(unsigned long long*)dst = pk.u64;
        } else {
            _Float16* dst = v + ((size_t)b * C_ + obase + quad * 4) * N_ + n;
#pragma unroll
            for (int r = 0; r < 4; ++r) dst[(size_t)r * N_] = (_Float16)acc[r];
        }
    }
}

// ---------------- flash attention, key-split: writes partial O/m/l ----------------
// Grid (64 qtile, 4 b, 4 ks). Block: 4 waves x 16 queries; softmax wave-local.
__global__ __launch_bounds__(256, 4) void attn_kernel(
    const _Float16* __restrict__ qt,     // (B,N,C)
    const _Float16* __restrict__ kt,     // (B,N,C)
    const _Float16* __restrict__ v,      // (B,C,N)
    _Float16* __restrict__ O_part,       // [b][qt][ks][q64][c256] f16
    float* __restrict__ m_part,          // [b][qt][ks][q64]
    float* __restrict__ l_part) {
    const int b = blockIdx.y;
    const int qt_i = blockIdx.x;
    const int ks = blockIdx.z;
    const int q0 = qt_i * 64;
    const int tid = threadIdx.x;
    const int w = tid >> 6;
    const int L = tid & 63;
    const int lane15 = L & 15;
    const int quad = L >> 4;

    __shared__ _Float16 Kt_s[TK][260];   // stride 130 dw -> 2-way max (free)
    __shared__ _Float16 Vs[C_][36];      // stride 18 dw  -> 2-way max (free)
    __shared__ _Float16 Ps[4][16][36];
    __shared__ float alpha_s[4][16];

    // Q A-frags: A[m=q][k=c]
    halfx8 qfrag[8];
    {
        const _Float16* qrow = qt + ((size_t)b * N_ + q0 + w * 16 + lane15) * C_ + quad * 8;
#pragma unroll
        for (int cs = 0; cs < 8; ++cs) qfrag[cs] = *(const halfx8*)(qrow + cs * 32);
    }

    floatx4 o_acc[16];
#pragma unroll
    for (int i = 0; i < 16; ++i) o_acc[i] = (floatx4){0.f, 0.f, 0.f, 0.f};
    float m_r[4], l_r[4];
#pragma unroll
    for (int r = 0; r < 4; ++r) { m_r[r] = -1e30f; l_r[r] = 0.f; }

    const _Float16* ktb = kt + (size_t)b * N_ * C_;
    const _Float16* vb  = v  + (size_t)b * C_ * N_;

    const int kbeg = ks * 1024;
    for (int k0 = kbeg; k0 < kbeg + 1024; k0 += TK) {
        // ---- stage K (32 x 256) and V (256 x 32) ----
#pragma unroll
        for (int p = 0; p < 4; ++p) {
            int idx = p * 256 + tid;
            int key = idx >> 5;
            int ch  = idx & 31;
            halfx8 val = *(const halfx8*)(ktb + (size_t)(k0 + key) * C_ + ch * 8);
            *(halfx8*)(&Kt_s[key][ch * 8]) = val;
        }
#pragma unroll
        for (int p = 0; p < 4; ++p) {
            int idx = p * 256 + tid;
            int c  = idx >> 2;
            int ch = idx & 3;
            halfx8 val = *(const halfx8*)(vb + (size_t)c * N_ + k0 + ch * 8);
            *(halfx8*)(&Vs[c][ch * 8]) = val;
        }
        __syncthreads();

        // ---- S = Q K^T: row q = quad*4+r, col key = lane15 + 16*ktile ----
        floatx4 s_acc[2];
        s_acc[0] = (floatx4){0.f, 0.f, 0.f, 0.f};
        s_acc[1] = (floatx4){0.f, 0.f, 0.f, 0.f};
#pragma unroll
        for (int ktile = 0; ktile < 2; ++ktile) {
            const _Float16* krow = &Kt_s[ktile * 16 + lane15][quad * 8];
#pragma unroll
            for (int cs = 0; cs < 8; ++cs) {
                halfx8 bf = *(const halfx8*)(krow + cs * 32);
                s_acc[ktile] = __builtin_amdgcn_mfma_f32_16x16x32_f16(qfrag[cs], bf, s_acc[ktile], 0, 0, 0);
            }
        }

        // ---- online softmax (wave-local) ----
        float rmax[4], psum[4], p0[4], p1[4], alpha[4];
#pragma unroll
        for (int r = 0; r < 4; ++r) rmax[r] = fmaxf(s_acc[0][r], s_acc[1][r]);
#pragma unroll
        for (int mask = 1; mask <= 8; mask <<= 1)
#pragma unroll
            for (int r = 0; r < 4; ++r) rmax[r] = fmaxf(rmax[r], __shfl_xor(rmax[r], mask));
#pragma unroll
        for (int r = 0; r < 4; ++r) {
            float mn = fmaxf(m_r[r], rmax[r]);
            alpha[r] = __expf(m_r[r] - mn);
            m_r[r] = mn;
            p0[r] = __expf(s_acc[0][r] - mn);
            p1[r] = __expf(s_acc[1][r] - mn);
            psum[r] = p0[r] + p1[r];
        }
#pragma unroll
        for (int mask = 1; mask <= 8; mask <<= 1)
#pragma unroll
            for (int r = 0; r < 4; ++r) psum[r] += __shfl_xor(psum[r], mask);
#pragma unroll
        for (int r = 0; r < 4; ++r) l_r[r] = l_r[r] * alpha[r] + psum[r];

        // ---- P -> LDS (C-layout), alpha broadcast ----
#pragma unroll
        for (int r = 0; r < 4; ++r) {
            Ps[w][quad * 4 + r][lane15]      = (_Float16)p0[r];
            Ps[w][quad * 4 + r][16 + lane15] = (_Float16)p1[r];
        }
        if (lane15 == 0) {
#pragma unroll
            for (int r = 0; r < 4; ++r) alpha_s[w][quad * 4 + r] = alpha[r];
        }
        __syncthreads();

        // ---- O *= alpha; O += V P^T ----
        float av = alpha_s[w][lane15];
#pragma unroll
        for (int i = 0; i < 16; ++i) {
            o_acc[i][0] *= av; o_acc[i][1] *= av; o_acc[i][2] *= av; o_acc[i][3] *= av;
        }
        halfx8 pfrag = *(const halfx8*)(&Ps[w][lane15][quad * 8]);   // B[k=key][n=q]
#pragma unroll
        for (int ct = 0; ct < 16; ++ct) {
            halfx8 vf = *(const halfx8*)(&Vs[ct * 16 + lane15][quad * 8]);  // A[m=c][k=key]
            o_acc[ct] = __builtin_amdgcn_mfma_f32_16x16x32_f16(vf, pfrag, o_acc[ct], 0, 0, 0);
        }
        __syncthreads();
    }

    // ---- store partials (unnormalized O, m, l) ----
    const size_t pbase = ((size_t)(b * 64 + qt_i)) * 4 + ks;
    _Float16* ob = O_part + (pbase * 64 + (w * 16 + lane15)) * 256;
#pragma unroll
    for (int ct = 0; ct < 16; ++ct) {
        union { _Float16 h[4]; unsigned long long u64; } pk;
#pragma unroll
        for (int r = 0; r < 4; ++r) pk.h[r] = (_Float16)o_acc[ct][r];
        *(unsigned long long*)(ob + ct * 16 + quad * 4) = pk.u64;
    }
    if (lane15 == 0) {
        float* mb = m_part + pbase * 64 + w * 16 + quad * 4;
        float* lb = l_part + pbase * 64 + w * 16 + quad * 4;
#pragma unroll
        for (int r = 0; r < 4; ++r) { mb[r] = m_r[r]; lb[r] = l_r[r]; }
    }
}

// ---------------- combine partials + epilogue ----------------
__global__ __launch_bounds__(256) void reduce_kernel(
    const void* __restrict__ x_raw,
    const _Float16* __restrict__ O_part,
    const float* __restrict__ m_part,
    const float* __restrict__ l_part,
    const void* __restrict__ gamma_p,
    void* __restrict__ out,
    const int* __restrict__ flag) {
    const int isf32 = *flag;
    const int qt_i = blockIdx.x;
    const int b = blockIdx.y;
    const int tid = threadIdx.x;
    __shared__ float ms[4][64], ls[4][64];
    {
        int ksi = tid >> 6, q = tid & 63;
        size_t base = (((size_t)(b * 64 + qt_i)) * 4 + ksi) * 64 + q;
        ms[ksi][q] = m_part[base];
        ls[ksi][q] = l_part[base];
    }
    __syncthreads();
    const int q = tid & 63;        // lane index -> coalesced n
    const int wv = tid >> 6;       // wave -> c range
    float M = fmaxf(fmaxf(ms[0][q], ms[1][q]), fmaxf(ms[2][q], ms[3][q]));
    float w0 = __expf(ms[0][q] - M), w1 = __expf(ms[1][q] - M),
          w2 = __expf(ms[2][q] - M), w3 = __expf(ms[3][q] - M);
    float denom = w0 * ls[0][q] + w1 * ls[1][q] + w2 * ls[2][q] + w3 * ls[3][q];
    float g = isf32 ? ((const float*)gamma_p)[0] : bf16_to_f(((const uint16_t*)gamma_p)[0]);
    float s = g / denom;
    const _Float16* o0 = O_part + (((size_t)(b * 64 + qt_i)) * 4) * 16384 + (size_t)q * 256;
    const int n = qt_i * 64 + q;
    for (int i = 0; i < 64; ++i) {
        int c = wv * 64 + i;
        float acc = w0 * (float)o0[c] + w1 * (float)o0[16384 + c]
                  + w2 * (float)o0[32768 + c] + w3 * (float)o0[49152 + c];
        size_t off = ((size_t)b * 256 + c) * 4096 + n;
        float xv = isf32 ? ((const float*)x_raw)[off] : bf16_to_f(((const uint16_t*)x_raw)[off]);
        float val = s * acc + xv;
        if (isf32) ((float*)out)[off] = val;
        else ((uint16_t*)out)[off] = f_to_bf16(val);
    }
}

// ---------------- fallback: monolithic attn (round-2, small ws) ----------------
__global__ __launch_bounds__(256, 2) void attn_full_kernel(
    const void* __restrict__ x_raw,
    const _Float16* __restrict__ qt,
    const _Float16* __restrict__ kt,
    const _Float16* __restrict__ v,
    const void* __restrict__ gamma_p,
    void* __restrict__ out,
    const int* __restrict__ flag) {
    const int isf32 = *flag;
    const int b = blockIdx.y;
    const int q0 = blockIdx.x * 64;
    const int tid = threadIdx.x;
    const int w = tid >> 6;
    const int L = tid & 63;
    const int lane15 = L & 15;
    const int quad = L >> 4;

    __shared__ _Float16 Kt_s[TK][260];
    __shared__ _Float16 Vs[C_][36];
    __shared__ _Float16 Ps[4][16][36];
    __shared__ float alpha_s[4][16];
    __shared__ float l_s[4][16];

    halfx8 qfrag[8];
    {
        const _Float16* qrow = qt + ((size_t)b * N_ + q0 + w * 16 + lane15) * C_ + quad * 8;
#pragma unroll
        for (int cs = 0; cs < 8; ++cs) qfrag[cs] = *(const halfx8*)(qrow + cs * 32);
    }
    floatx4 o_acc[16];
#pragma unroll
    for (int i = 0; i < 16; ++i) o_acc[i] = (floatx4){0.f, 0.f, 0.f, 0.f};
    float m_r[4], l_r[4];
#pragma unroll
    for (int r = 0; r < 4; ++r) { m_r[r] = -1e30f; l_r[r] = 0.f; }
    const _Float16* ktb = kt + (size_t)b * N_ * C_;
    const _Float16* vb  = v  + (size_t)b * C_ * N_;

    for (int k0 = 0; k0 < N_; k0 += TK) {
#pragma unroll
        for (int p = 0; p < 4; ++p) {
            int idx = p * 256 + tid;
            int key = idx >> 5, ch = idx & 31;
            *(halfx8*)(&Kt_s[key][ch * 8]) =
                *(const halfx8*)(ktb + (size_t)(k0 + key) * C_ + ch * 8);
        }
#pragma unroll
        for (int p = 0; p < 4; ++p) {
            int idx = p * 256 + tid;
            int c = idx >> 2, ch = idx & 3;
            *(halfx8*)(&Vs[c][ch * 8]) =
                *(const halfx8*)(vb + (size_t)c * N_ + k0 + ch * 8);
        }
        __syncthreads();
        floatx4 s_acc[2];
        s_acc[0] = (floatx4){0.f, 0.f, 0.f, 0.f};
        s_acc[1] = (floatx4){0.f, 0.f, 0.f, 0.f};
#pragma unroll
        for (int ktile = 0; ktile < 2; ++ktile) {
            const _Float16* krow = &Kt_s[ktile * 16 + lane15][quad * 8];
#pragma unroll
            for (int cs = 0; cs < 8; ++cs) {
                halfx8 bf = *(const halfx8*)(krow + cs * 32);
                s_acc[ktile] = __builtin_amdgcn_mfma_f32_16x16x32_f16(qfrag[cs], bf, s_acc[ktile], 0, 0, 0);
            }
        }
        float rmax[4], psum[4], p0[4], p1[4], alpha[4];
#pragma unroll
        for (int r = 0; r < 4; ++r) rmax[r] = fmaxf(s_acc[0][r], s_acc[1][r]);
#pragma unroll
        for (int mask = 1; mask <= 8; mask <<= 1)
#pragma unroll
            for (int r = 0; r < 4; ++r) rmax[r] = fmaxf(rmax[r], __shfl_xor(rmax[r], mask));
#pragma unroll
        for (int r = 0; r < 4; ++r) {
            float mn = fmaxf(m_r[r], rmax[r]);
            alpha[r] = __expf(m_r[r] - mn);
            m_r[r] = mn;
            p0[r] = __expf(s_acc[0][r] - mn);
            p1[r] = __expf(s_acc[1][r] - mn);
            psum[r] = p0[r] + p1[r];
        }
#pragma unroll
        for (int mask = 1; mask <= 8; mask <<= 1)
#pragma unroll
            for (int r = 0; r < 4; ++r) psum[r] += __shfl_xor(psum[r], mask);
#pragma unroll
        for (int r = 0; r < 4; ++r) l_r[r] = l_r[r] * alpha[r] + psum[r];
#pragma unroll
        for (int r = 0; r < 4; ++r) {
            Ps[w][quad * 4 + r][lane15]      = (_Float16)p0[r];
            Ps[w][quad * 4 + r][16 + lane15] = (_Float16)p1[r];
        }
        if (lane15 == 0) {
#pragma unroll
            for (int r = 0; r < 4; ++r) alpha_s[w][quad * 4 + r] = alpha[r];
        }
        __syncthreads();
        float av = alpha_s[w][lane15];
#pragma unroll
        for (int i = 0; i < 16; ++i) {
            o_acc[i][0] *= av; o_acc[i][1] *= av; o_acc[i][2] *= av; o_acc[i][3] *= av;
        }
        halfx8 pfrag = *(const halfx8*)(&Ps[w][lane15][quad * 8]);
#pragma unroll
        for (int ct = 0; ct < 16; ++ct) {
            halfx8 vf = *(const halfx8*)(&Vs[ct * 16 + lane15][quad * 8]);
            o_acc[ct] = __builtin_amdgcn_mfma_f32_16x16x32_f16(vf, pfrag, o_acc[ct], 0, 0, 0);
        }
        __syncthreads();
    }
    if (lane15 == 0) {
#pragma unroll
        for (int r = 0; r < 4; ++r) l_s[w][quad * 4 + r] = l_r[r];
    }
    __syncthreads();
    float linv = 1.0f / l_s[w][lane15];
    float g = isf32 ? ((const float*)gamma_p)[0] : bf16_to_f(((const uint16_t*)gamma_p)[0]);
    const int n_out = q0 + w * 16 + lane15;
#pragma unroll
    for (int ct = 0; ct < 16; ++ct)
#pragma unroll
        for (int r = 0; r < 4; ++r) {
            int c = ct * 16 + quad * 4 + r;
            size_t off = ((size_t)b * C_ + c) * N_ + n_out;
            float val = g * o_acc[ct][r] * linv +
                        (isf32 ? ((const float*)x_raw)[off] : bf16_to_f(((const uint16_t*)x_raw)[off]));
            if (isf32) ((float*)out)[off] = val;
            else ((uint16_t*)out)[off] = f_to_bf16(val);
        }
}

// ---------------- launcher ----------------
extern "C" void kernel_launch(void* const* d_in, const int* in_sizes, int n_in,
                              void* d_out, int out_size, void* d_ws, size_t ws_size,
                              hipStream_t stream) {
    const void* x  = d_in[0];
    const void* wq = d_in[1];
    const void* wk = d_in[2];
    const void* wv = d_in[3];
    const void* gm = d_in[4];

    char* ws = (char*)d_ws;
    int* flag    = (int*)ws;
    _Float16* wf = (_Float16*)(ws + 4096);
    size_t o0 = 4096 + 393216;
    _Float16* qt = (_Float16*)(ws + o0);
    _Float16* kt = (_Float16*)(ws + o0 + 8388608);
    _Float16* v  = (_Float16*)(ws + o0 + 2 * 8388608);
    size_t o1 = o0 + 3 * 8388608;                       // 25,563,136
    _Float16* opart = (_Float16*)(ws + o1);             // 33,554,432 B
    float* mpart = (float*)(ws + o1 + 33554432);        // 262,144 B
    float* lpart = (float*)(ws + o1 + 33554432 + 262144);
    const size_t need = o1 + 33554432 + 2 * 262144;     // ~59.6 MB

    sniff_kernel<<<dim3(1), dim3(256), 0, stream>>>((const uint16_t*)wq, flag);
    wconv_kernel<<<dim3(768), dim3(256), 0, stream>>>(wq, wk, wv, wf, flag);
    proj_kernel<<<dim3(64, 4, 3), dim3(256), 0, stream>>>(x, wf, qt, kt, v, flag);
    if (ws_size >= need) {
        attn_kernel<<<dim3(64, 4, 4), dim3(256), 0, stream>>>(qt, kt, v, opart, mpart, lpart);
        reduce_kernel<<<dim3(64, 4), dim3(256), 0, stream>>>(x, opart, mpart, lpart, gm, d_out, flag);
    } else {
        attn_full_kernel<<<dim3(64, 4), dim3(256), 0, stream>>>(x, qt, kt, v, gm, d_out, flag);
    }
}

// Round 4
// 644.042 us; speedup vs baseline: 1.2607x; 1.2607x over previous
//
#include <hip/hip_runtime.h>
#include <stdint.h>

#define B_ 4
#define C_ 256
#define N_ 4096
#define TK 32

using floatx4 = __attribute__((ext_vector_type(4))) float;
using halfx8  = __attribute__((ext_vector_type(8))) _Float16;

__device__ __forceinline__ float bf16_to_f(uint16_t u) {
    union { uint32_t u; float f; } c; c.u = ((uint32_t)u) << 16; return c.f;
}
__device__ __forceinline__ uint16_t f_to_bf16(float f) {
    union { float f; uint32_t u; } c; c.f = f;
    uint32_t u = c.u;
    u += 0x7FFFu + ((u >> 16) & 1u);   // RNE
    return (uint16_t)(u >> 16);
}

// ---------------- sniff input dtype (1 = f32, 0 = bf16) ----------------
__global__ void sniff_kernel(const uint16_t* __restrict__ wq_u16, int* __restrict__ flag) {
    __shared__ int cnt;
    if (threadIdx.x == 0) cnt = 0;
    __syncthreads();
    int local = 0;
    for (int i = threadIdx.x; i < 8192; i += 256) {
        int e = (wq_u16[i] >> 7) & 0xFF;
        if (e >= 132) local++;
    }
    atomicAdd(&cnt, local);
    __syncthreads();
    if (threadIdx.x == 0) *flag = (cnt > 64) ? 1 : 0;
}

// ---------------- W -> f16 ----------------
__global__ void wconv_kernel(const void* __restrict__ wq,
                             const void* __restrict__ wk,
                             const void* __restrict__ wv,
                             _Float16* __restrict__ wf,
                             const int* __restrict__ flag) {
    const int isf32 = *flag;
    int idx = blockIdx.x * 256 + threadIdx.x;
    int mat = idx >> 16;
    int off = idx & 65535;
    const void* src = (mat == 0) ? wq : ((mat == 1) ? wk : wv);
    float v = isf32 ? ((const float*)src)[off] : bf16_to_f(((const uint16_t*)src)[off]);
    wf[idx] = (_Float16)v;
}

// ---------------- QKV projection (MFMA f16), mat = blockIdx.z ----------------
__global__ __launch_bounds__(256) void proj_kernel(
    const void* __restrict__ x_raw,      // (B,C,N) bf16 or f32
    const _Float16* __restrict__ wf,     // 3 x (C,C) f16
    _Float16* __restrict__ qt,           // (B,N,C)
    _Float16* __restrict__ kt,           // (B,N,C)
    _Float16* __restrict__ v,            // (B,C,N)
    const int* __restrict__ flag) {
    const int isf32 = *flag;
    const int b = blockIdx.y;
    const int mat = blockIdx.z;
    const int n0 = blockIdx.x * 64;
    const int tid = threadIdx.x;
    const int w = tid >> 6;
    const int L = tid & 63;
    const int lane15 = L & 15;
    const int quad = L >> 4;
    const int n = n0 + w * 16 + lane15;

    // B-frags: B[k=c][n], lane holds c = cs*32 + quad*8 + j
    halfx8 bfrag[8];
    const size_t xbase = (size_t)b * C_ * N_;
    if (isf32) {
        const float* xb = (const float*)x_raw + xbase;
#pragma unroll
        for (int cs = 0; cs < 8; ++cs) {
            const int cbase = cs * 32 + quad * 8;
            halfx8 f;
#pragma unroll
            for (int j = 0; j < 8; ++j)
                f[j] = (_Float16)xb[(size_t)(cbase + j) * N_ + n];
            bfrag[cs] = f;
        }
    } else {
        const uint16_t* xb = (const uint16_t*)x_raw + xbase;
#pragma unroll
        for (int cs = 0; cs < 8; ++cs) {
            const int cbase = cs * 32 + quad * 8;
            halfx8 f;
#pragma unroll
            for (int j = 0; j < 8; ++j)
                f[j] = (_Float16)bf16_to_f(xb[(size_t)(cbase + j) * N_ + n]);
            bfrag[cs] = f;
        }
    }

    const _Float16* wm = wf + mat * (C_ * C_);
#pragma unroll 4
    for (int ot = 0; ot < 16; ++ot) {
        const int obase = ot * 16;
        floatx4 acc = {0.f, 0.f, 0.f, 0.f};
        const _Float16* wrow = wm + (size_t)(obase + lane15) * C_ + quad * 8;
#pragma unroll
        for (int cs = 0; cs < 8; ++cs) {
            halfx8 af = *(const halfx8*)(wrow + cs * 32);
            acc = __builtin_amdgcn_mfma_f32_16x16x32_f16(af, bfrag[cs], acc, 0, 0, 0);
        }
        // D[o][n]: col n = lane15, row o = obase + quad*4 + r
        if (mat < 2) {
            _Float16* dst = (mat == 0 ? qt : kt) +
                            ((size_t)b * N_ + n) * C_ + obase + quad * 4;
            union { _Float16 h[4]; unsigned long long u64; } pk;
#pragma unroll
            for (int r = 0; r < 4; ++r) pk.h[r] = (_Float16)acc[r];
            *(unsigned long long*)dst = pk.u64;
        } else {
            _Float16* dst = v + ((size_t)b * C_ + obase + quad * 4) * N_ + n;
#pragma unroll
            for (int r = 0; r < 4; ++r) dst[(size_t)r * N_] = (_Float16)acc[r];
        }
    }
}

// ---------------- flash attention, key-split, XCD-swizzled 1D grid ----------------
// l = (combo&7) + 8*qtile + 512*(combo>>3); combo = b*4+ks. XCD = l%8 keeps one
// (b,ks) pair's K/V (1 MB) on one XCD L2 (2 combos/XCD = 2 MB < 4 MB).
__global__ __launch_bounds__(256, 4) void attn_kernel(
    const _Float16* __restrict__ qt,     // (B,N,C)
    const _Float16* __restrict__ kt,     // (B,N,C)
    const _Float16* __restrict__ v,      // (B,C,N)
    _Float16* __restrict__ O_part,       // [b][qt][ks][q64][c256] f16
    float* __restrict__ m_part,          // [b][qt][ks][q64]
    float* __restrict__ l_part) {
    const int l = blockIdx.x;
    const int combo = (l & 7) | ((l >> 9) << 3);
    const int qt_i = (l >> 3) & 63;
    const int b = combo >> 2;
    const int ks = combo & 3;
    const int q0 = qt_i * 64;
    const int tid = threadIdx.x;
    const int w = tid >> 6;
    const int L = tid & 63;
    const int lane15 = L & 15;
    const int quad = L >> 4;

    __shared__ _Float16 Kt_s[TK][260];   // stride 130 dw -> 2-way max (free)
    __shared__ _Float16 Vs[C_][36];      // stride 18 dw  -> 2-way max (free)
    __shared__ _Float16 Ps[4][16][36];
    __shared__ float alpha_s[4][16];
    __shared__ float l_s[4][16];

    // Q A-frags: A[m=q][k=c]
    halfx8 qfrag[8];
    {
        const _Float16* qrow = qt + ((size_t)b * N_ + q0 + w * 16 + lane15) * C_ + quad * 8;
#pragma unroll
        for (int cs = 0; cs < 8; ++cs) qfrag[cs] = *(const halfx8*)(qrow + cs * 32);
    }

    floatx4 o_acc[16];
#pragma unroll
    for (int i = 0; i < 16; ++i) o_acc[i] = (floatx4){0.f, 0.f, 0.f, 0.f};
    float m_r[4], l_r[4];
#pragma unroll
    for (int r = 0; r < 4; ++r) { m_r[r] = -1e30f; l_r[r] = 0.f; }

    const _Float16* ktb = kt + (size_t)b * N_ * C_;
    const _Float16* vb  = v  + (size_t)b * C_ * N_;

    const int kbeg = ks * 1024;
    for (int k0 = kbeg; k0 < kbeg + 1024; k0 += TK) {
        // ---- stage K (32 x 256) and V (256 x 32) ----
#pragma unroll
        for (int p = 0; p < 4; ++p) {
            int idx = p * 256 + tid;
            int key = idx >> 5;
            int ch  = idx & 31;
            halfx8 val = *(const halfx8*)(ktb + (size_t)(k0 + key) * C_ + ch * 8);
            *(halfx8*)(&Kt_s[key][ch * 8]) = val;
        }
#pragma unroll
        for (int p = 0; p < 4; ++p) {
            int idx = p * 256 + tid;
            int c  = idx >> 2;
            int ch = idx & 3;
            halfx8 val = *(const halfx8*)(vb + (size_t)c * N_ + k0 + ch * 8);
            *(halfx8*)(&Vs[c][ch * 8]) = val;
        }
        __syncthreads();

        // ---- S = Q K^T: row q = quad*4+r, col key = lane15 + 16*ktile ----
        floatx4 s_acc[2];
        s_acc[0] = (floatx4){0.f, 0.f, 0.f, 0.f};
        s_acc[1] = (floatx4){0.f, 0.f, 0.f, 0.f};
#pragma unroll
        for (int ktile = 0; ktile < 2; ++ktile) {
            const _Float16* krow = &Kt_s[ktile * 16 + lane15][quad * 8];
#pragma unroll
            for (int cs = 0; cs < 8; ++cs) {
                halfx8 bf = *(const halfx8*)(krow + cs * 32);
                s_acc[ktile] = __builtin_amdgcn_mfma_f32_16x16x32_f16(qfrag[cs], bf, s_acc[ktile], 0, 0, 0);
            }
        }

        // ---- online softmax (wave-local) ----
        float rmax[4], psum[4], p0[4], p1[4], alpha[4];
#pragma unroll
        for (int r = 0; r < 4; ++r) rmax[r] = fmaxf(s_acc[0][r], s_acc[1][r]);
#pragma unroll
        for (int mask = 1; mask <= 8; mask <<= 1)
#pragma unroll
            for (int r = 0; r < 4; ++r) rmax[r] = fmaxf(rmax[r], __shfl_xor(rmax[r], mask));
#pragma unroll
        for (int r = 0; r < 4; ++r) {
            float mn = fmaxf(m_r[r], rmax[r]);
            alpha[r] = __expf(m_r[r] - mn);
            m_r[r] = mn;
            p0[r] = __expf(s_acc[0][r] - mn);
            p1[r] = __expf(s_acc[1][r] - mn);
            psum[r] = p0[r] + p1[r];
        }
#pragma unroll
        for (int mask = 1; mask <= 8; mask <<= 1)
#pragma unroll
            for (int r = 0; r < 4; ++r) psum[r] += __shfl_xor(psum[r], mask);
#pragma unroll
        for (int r = 0; r < 4; ++r) l_r[r] = l_r[r] * alpha[r] + psum[r];

        // ---- P/alpha -> LDS; wave-local (per-wave DS is in-order): NO barrier ----
#pragma unroll
        for (int r = 0; r < 4; ++r) {
            Ps[w][quad * 4 + r][lane15]      = (_Float16)p0[r];
            Ps[w][quad * 4 + r][16 + lane15] = (_Float16)p1[r];
        }
        if (lane15 == 0) {
#pragma unroll
            for (int r = 0; r < 4; ++r) alpha_s[w][quad * 4 + r] = alpha[r];
        }

        // ---- O *= alpha; O += V P^T ----
        float av = alpha_s[w][lane15];
#pragma unroll
        for (int i = 0; i < 16; ++i) {
            o_acc[i][0] *= av; o_acc[i][1] *= av; o_acc[i][2] *= av; o_acc[i][3] *= av;
        }
        halfx8 pfrag = *(const halfx8*)(&Ps[w][lane15][quad * 8]);   // B[k=key][n=q]
#pragma unroll
        for (int ct = 0; ct < 16; ++ct) {
            halfx8 vf = *(const halfx8*)(&Vs[ct * 16 + lane15][quad * 8]);  // A[m=c][k=key]
            o_acc[ct] = __builtin_amdgcn_mfma_f32_16x16x32_f16(vf, pfrag, o_acc[ct], 0, 0, 0);
        }
        __syncthreads();   // all waves done reading Kt_s/Vs before restage
    }

    // ---- store partials (unnormalized O, m, l) ----
    const size_t pbase = ((size_t)(b * 64 + qt_i)) * 4 + ks;
    _Float16* ob = O_part + (pbase * 64 + (w * 16 + lane15)) * 256;
#pragma unroll
    for (int ct = 0; ct < 16; ++ct) {
        union { _Float16 h[4]; unsigned long long u64; } pk;
#pragma unroll
        for (int r = 0; r < 4; ++r) pk.h[r] = (_Float16)o_acc[ct][r];
        *(unsigned long long*)(ob + ct * 16 + quad * 4) = pk.u64;
    }
    if (lane15 == 0) {
        float* mb = m_part + pbase * 64 + w * 16 + quad * 4;
        float* lb = l_part + pbase * 64 + w * 16 + quad * 4;
#pragma unroll
        for (int r = 0; r < 4; ++r) { mb[r] = m_r[r]; lb[r] = l_r[r]; }
    }
    (void)l_s;
}

// ---------------- combine partials + epilogue (vectorized) ----------------
__global__ __launch_bounds__(256) void reduce_kernel(
    const void* __restrict__ x_raw,
    const _Float16* __restrict__ O_part,
    const float* __restrict__ m_part,
    const float* __restrict__ l_part,
    const void* __restrict__ gamma_p,
    void* __restrict__ out,
    const int* __restrict__ flag) {
    const int isf32 = *flag;
    const int qt_i = blockIdx.x;
    const int b = blockIdx.y;
    const int tid = threadIdx.x;
    const int q = tid & 63;        // lane -> coalesced n
    const int wv = tid >> 6;       // wave -> c range

    const size_t sbase = ((size_t)(b * 64 + qt_i)) * 4;
    float m0 = m_part[(sbase + 0) * 64 + q], m1 = m_part[(sbase + 1) * 64 + q],
          m2 = m_part[(sbase + 2) * 64 + q], m3 = m_part[(sbase + 3) * 64 + q];
    float l0 = l_part[(sbase + 0) * 64 + q], l1 = l_part[(sbase + 1) * 64 + q],
          l2 = l_part[(sbase + 2) * 64 + q], l3 = l_part[(sbase + 3) * 64 + q];
    float M = fmaxf(fmaxf(m0, m1), fmaxf(m2, m3));
    float w0 = __expf(m0 - M), w1 = __expf(m1 - M), w2 = __expf(m2 - M), w3 = __expf(m3 - M);
    float denom = w0 * l0 + w1 * l1 + w2 * l2 + w3 * l3;
    float g = isf32 ? ((const float*)gamma_p)[0] : bf16_to_f(((const uint16_t*)gamma_p)[0]);
    float s = g / denom;

    const _Float16* o0 = O_part + sbase * 16384 + (size_t)q * 256;
    const int n = qt_i * 64 + q;
#pragma unroll
    for (int ch = 0; ch < 8; ++ch) {
        const int c0 = wv * 64 + ch * 8;
        halfx8 a = *(const halfx8*)(o0 + c0);
        halfx8 bpart = *(const halfx8*)(o0 + 16384 + c0);
        halfx8 cpart = *(const halfx8*)(o0 + 32768 + c0);
        halfx8 dpart = *(const halfx8*)(o0 + 49152 + c0);
#pragma unroll
        for (int j = 0; j < 8; ++j) {
            float acc = w0 * (float)a[j] + w1 * (float)bpart[j]
                      + w2 * (float)cpart[j] + w3 * (float)dpart[j];
            size_t off = ((size_t)b * 256 + c0 + j) * 4096 + n;
            float xv = isf32 ? ((const float*)x_raw)[off] : bf16_to_f(((const uint16_t*)x_raw)[off]);
            float val = s * acc + xv;
            if (isf32) ((float*)out)[off] = val;
            else ((uint16_t*)out)[off] = f_to_bf16(val);
        }
    }
}

// ---------------- fallback: monolithic attn (small ws) ----------------
__global__ __launch_bounds__(256, 2) void attn_full_kernel(
    const void* __restrict__ x_raw,
    const _Float16* __restrict__ qt,
    const _Float16* __restrict__ kt,
    const _Float16* __restrict__ v,
    const void* __restrict__ gamma_p,
    void* __restrict__ out,
    const int* __restrict__ flag) {
    const int isf32 = *flag;
    const int b = blockIdx.y;
    const int q0 = blockIdx.x * 64;
    const int tid = threadIdx.x;
    const int w = tid >> 6;
    const int L = tid & 63;
    const int lane15 = L & 15;
    const int quad = L >> 4;

    __shared__ _Float16 Kt_s[TK][260];
    __shared__ _Float16 Vs[C_][36];
    __shared__ _Float16 Ps[4][16][36];
    __shared__ float alpha_s[4][16];
    __shared__ float l_s[4][16];

    halfx8 qfrag[8];
    {
        const _Float16* qrow = qt + ((size_t)b * N_ + q0 + w * 16 + lane15) * C_ + quad * 8;
#pragma unroll
        for (int cs = 0; cs < 8; ++cs) qfrag[cs] = *(const halfx8*)(qrow + cs * 32);
    }
    floatx4 o_acc[16];
#pragma unroll
    for (int i = 0; i < 16; ++i) o_acc[i] = (floatx4){0.f, 0.f, 0.f, 0.f};
    float m_r[4], l_r[4];
#pragma unroll
    for (int r = 0; r < 4; ++r) { m_r[r] = -1e30f; l_r[r] = 0.f; }
    const _Float16* ktb = kt + (size_t)b * N_ * C_;
    const _Float16* vb  = v  + (size_t)b * C_ * N_;

    for (int k0 = 0; k0 < N_; k0 += TK) {
#pragma unroll
        for (int p = 0; p < 4; ++p) {
            int idx = p * 256 + tid;
            int key = idx >> 5, ch = idx & 31;
            *(halfx8*)(&Kt_s[key][ch * 8]) =
                *(const halfx8*)(ktb + (size_t)(k0 + key) * C_ + ch * 8);
        }
#pragma unroll
        for (int p = 0; p < 4; ++p) {
            int idx = p * 256 + tid;
            int c = idx >> 2, ch = idx & 3;
            *(halfx8*)(&Vs[c][ch * 8]) =
                *(const halfx8*)(vb + (size_t)c * N_ + k0 + ch * 8);
        }
        __syncthreads();
        floatx4 s_acc[2];
        s_acc[0] = (floatx4){0.f, 0.f, 0.f, 0.f};
        s_acc[1] = (floatx4){0.f, 0.f, 0.f, 0.f};
#pragma unroll
        for (int ktile = 0; ktile < 2; ++ktile) {
            const _Float16* krow = &Kt_s[ktile * 16 + lane15][quad * 8];
#pragma unroll
            for (int cs = 0; cs < 8; ++cs) {
                halfx8 bf = *(const halfx8*)(krow + cs * 32);
                s_acc[ktile] = __builtin_amdgcn_mfma_f32_16x16x32_f16(qfrag[cs], bf, s_acc[ktile], 0, 0, 0);
            }
        }
        float rmax[4], psum[4], p0[4], p1[4], alpha[4];
#pragma unroll
        for (int r = 0; r < 4; ++r) rmax[r] = fmaxf(s_acc[0][r], s_acc[1][r]);
#pragma unroll
        for (int mask = 1; mask <= 8; mask <<= 1)
#pragma unroll
            for (int r = 0; r < 4; ++r) rmax[r] = fmaxf(rmax[r], __shfl_xor(rmax[r], mask));
#pragma unroll
        for (int r = 0; r < 4; ++r) {
            float mn = fmaxf(m_r[r], rmax[r]);
            alpha[r] = __expf(m_r[r] - mn);
            m_r[r] = mn;
            p0[r] = __expf(s_acc[0][r] - mn);
            p1[r] = __expf(s_acc[1][r] - mn);
            psum[r] = p0[r] + p1[r];
        }
#pragma unroll
        for (int mask = 1; mask <= 8; mask <<= 1)
#pragma unroll
            for (int r = 0; r < 4; ++r) psum[r] += __shfl_xor(psum[r], mask);
#pragma unroll
        for (int r = 0; r < 4; ++r) l_r[r] = l_r[r] * alpha[r] + psum[r];
#pragma unroll
        for (int r = 0; r < 4; ++r) {
            Ps[w][quad * 4 + r][lane15]      = (_Float16)p0[r];
            Ps[w][quad * 4 + r][16 + lane15] = (_Float16)p1[r];
        }
        if (lane15 == 0) {
#pragma unroll
            for (int r = 0; r < 4; ++r) alpha_s[w][quad * 4 + r] = alpha[r];
        }
        __syncthreads();
        float av = alpha_s[w][lane15];
#pragma unroll
        for (int i = 0; i < 16; ++i) {
            o_acc[i][0] *= av; o_acc[i][1] *= av; o_acc[i][2] *= av; o_acc[i][3] *= av;
        }
        halfx8 pfrag = *(const halfx8*)(&Ps[w][lane15][quad * 8]);
#pragma unroll
        for (int ct = 0; ct < 16; ++ct) {
            halfx8 vf = *(const halfx8*)(&Vs[ct * 16 + lane15][quad * 8]);
            o_acc[ct] = __builtin_amdgcn_mfma_f32_16x16x32_f16(vf, pfrag, o_acc[ct], 0, 0, 0);
        }
        __syncthreads();
    }
    if (lane15 == 0) {
#pragma unroll
        for (int r = 0; r < 4; ++r) l_s[w][quad * 4 + r] = l_r[r];
    }
    __syncthreads();
    float linv = 1.0f / l_s[w][lane15];
    float g = isf32 ? ((const float*)gamma_p)[0] : bf16_to_f(((const uint16_t*)gamma_p)[0]);
    const int n_out = q0 + w * 16 + lane15;
#pragma unroll
    for (int ct = 0; ct < 16; ++ct)
#pragma unroll
        for (int r = 0; r < 4; ++r) {
            int c = ct * 16 + quad * 4 + r;
            size_t off = ((size_t)b * C_ + c) * N_ + n_out;
            float val = g * o_acc[ct][r] * linv +
                        (isf32 ? ((const float*)x_raw)[off] : bf16_to_f(((const uint16_t*)x_raw)[off]));
            if (isf32) ((float*)out)[off] = val;
            else ((uint16_t*)out)[off] = f_to_bf16(val);
        }
}

// ---------------- launcher ----------------
extern "C" void kernel_launch(void* const* d_in, const int* in_sizes, int n_in,
                              void* d_out, int out_size, void* d_ws, size_t ws_size,
                              hipStream_t stream) {
    const void* x  = d_in[0];
    const void* wq = d_in[1];
    const void* wk = d_in[2];
    const void* wv = d_in[3];
    const void* gm = d_in[4];

    char* ws = (char*)d_ws;
    int* flag    = (int*)ws;
    _Float16* wf = (_Float16*)(ws + 4096);
    size_t o0 = 4096 + 393216;
    _Float16* qt = (_Float16*)(ws + o0);
    _Float16* kt = (_Float16*)(ws + o0 + 8388608);
    _Float16* v  = (_Float16*)(ws + o0 + 2 * 8388608);
    size_t o1 = o0 + 3 * 8388608;                       // 25,563,136
    _Float16* opart = (_Float16*)(ws + o1);             // 33,554,432 B
    float* mpart = (float*)(ws + o1 + 33554432);        // 262,144 B
    float* lpart = (float*)(ws + o1 + 33554432 + 262144);
    const size_t need = o1 + 33554432 + 2 * 262144;     // ~59.6 MB

    sniff_kernel<<<dim3(1), dim3(256), 0, stream>>>((const uint16_t*)wq, flag);
    wconv_kernel<<<dim3(768), dim3(256), 0, stream>>>(wq, wk, wv, wf, flag);
    proj_kernel<<<dim3(64, 4, 3), dim3(256), 0, stream>>>(x, wf, qt, kt, v, flag);
    if (ws_size >= need) {
        attn_kernel<<<dim3(1024), dim3(256), 0, stream>>>(qt, kt, v, opart, mpart, lpart);
        reduce_kernel<<<dim3(64, 4), dim3(256), 0, stream>>>(x, opart, mpart, lpart, gm, d_out, flag);
    } else {
        attn_full_kernel<<<dim3(64, 4), dim3(256), 0, stream>>>(x, qt, kt, v, gm, d_out, flag);
    }
}

// Round 5
// 567.340 us; speedup vs baseline: 1.4311x; 1.1352x over previous
//
#include <hip/hip_runtime.h>
#include <stdint.h>

#define B_ 4
#define C_ 256
#define N_ 4096
#define TK 32

using floatx4 = __attribute__((ext_vector_type(4))) float;
using halfx8  = __attribute__((ext_vector_type(8))) _Float16;

__device__ __forceinline__ float bf16_to_f(uint16_t u) {
    union { uint32_t u; float f; } c; c.u = ((uint32_t)u) << 16; return c.f;
}
__device__ __forceinline__ uint16_t f_to_bf16(float f) {
    union { float f; uint32_t u; } c; c.f = f;
    uint32_t u = c.u;
    u += 0x7FFFu + ((u >> 16) & 1u);   // RNE
    return (uint16_t)(u >> 16);
}

// ---------------- sniff input dtype (1 = f32, 0 = bf16) ----------------
__global__ void sniff_kernel(const uint16_t* __restrict__ wq_u16, int* __restrict__ flag) {
    __shared__ int cnt;
    if (threadIdx.x == 0) cnt = 0;
    __syncthreads();
    int local = 0;
    for (int i = threadIdx.x; i < 8192; i += 256) {
        int e = (wq_u16[i] >> 7) & 0xFF;
        if (e >= 132) local++;
    }
    atomicAdd(&cnt, local);
    __syncthreads();
    if (threadIdx.x == 0) *flag = (cnt > 64) ? 1 : 0;
}

// ---------------- W -> f16 ----------------
__global__ void wconv_kernel(const void* __restrict__ wq,
                             const void* __restrict__ wk,
                             const void* __restrict__ wv,
                             _Float16* __restrict__ wf,
                             const int* __restrict__ flag) {
    const int isf32 = *flag;
    int idx = blockIdx.x * 256 + threadIdx.x;
    int mat = idx >> 16;
    int off = idx & 65535;
    const void* src = (mat == 0) ? wq : ((mat == 1) ? wk : wv);
    float v = isf32 ? ((const float*)src)[off] : bf16_to_f(((const uint16_t*)src)[off]);
    wf[idx] = (_Float16)v;
}

// ---------------- QKV projection (MFMA f16), mat = blockIdx.z ----------------
__global__ __launch_bounds__(256) void proj_kernel(
    const void* __restrict__ x_raw,      // (B,C,N) bf16 or f32
    const _Float16* __restrict__ wf,     // 3 x (C,C) f16
    _Float16* __restrict__ qt,           // (B,N,C)
    _Float16* __restrict__ kt,           // (B,N,C)
    _Float16* __restrict__ v,            // (B,C,N)
    const int* __restrict__ flag) {
    const int isf32 = *flag;
    const int b = blockIdx.y;
    const int mat = blockIdx.z;
    const int n0 = blockIdx.x * 64;
    const int tid = threadIdx.x;
    const int w = tid >> 6;
    const int L = tid & 63;
    const int lane15 = L & 15;
    const int quad = L >> 4;
    const int n = n0 + w * 16 + lane15;

    // B-frags: B[k=c][n], lane holds c = cs*32 + quad*8 + j
    halfx8 bfrag[8];
    const size_t xbase = (size_t)b * C_ * N_;
    if (isf32) {
        const float* xb = (const float*)x_raw + xbase;
#pragma unroll
        for (int cs = 0; cs < 8; ++cs) {
            const int cbase = cs * 32 + quad * 8;
            halfx8 f;
#pragma unroll
            for (int j = 0; j < 8; ++j)
                f[j] = (_Float16)xb[(size_t)(cbase + j) * N_ + n];
            bfrag[cs] = f;
        }
    } else {
        const uint16_t* xb = (const uint16_t*)x_raw + xbase;
#pragma unroll
        for (int cs = 0; cs < 8; ++cs) {
            const int cbase = cs * 32 + quad * 8;
            halfx8 f;
#pragma unroll
            for (int j = 0; j < 8; ++j)
                f[j] = (_Float16)bf16_to_f(xb[(size_t)(cbase + j) * N_ + n]);
            bfrag[cs] = f;
        }
    }

    const _Float16* wm = wf + mat * (C_ * C_);
#pragma unroll 4
    for (int ot = 0; ot < 16; ++ot) {
        const int obase = ot * 16;
        floatx4 acc = {0.f, 0.f, 0.f, 0.f};
        const _Float16* wrow = wm + (size_t)(obase + lane15) * C_ + quad * 8;
#pragma unroll
        for (int cs = 0; cs < 8; ++cs) {
            halfx8 af = *(const halfx8*)(wrow + cs * 32);
            acc = __builtin_amdgcn_mfma_f32_16x16x32_f16(af, bfrag[cs], acc, 0, 0, 0);
        }
        // D[o][n]: col n = lane15, row o = obase + quad*4 + r
        if (mat < 2) {
            _Float16* dst = (mat == 0 ? qt : kt) +
                            ((size_t)b * N_ + n) * C_ + obase + quad * 4;
            union { _Float16 h[4]; unsigned long long u64; } pk;
#pragma unroll
            for (int r = 0; r < 4; ++r) pk.h[r] = (_Float16)acc[r];
            *(unsigned long long*)dst = pk.u64;
        } else {
            _Float16* dst = v + ((size_t)b * C_ + obase + quad * 4) * N_ + n;
#pragma unroll
            for (int r = 0; r < 4; ++r) dst[(size_t)r * N_] = (_Float16)acc[r];
        }
    }
}

// ---------------- flash attention: Qtile=128, key-split 4, XCD-swizzled ----------------
// 512 blocks x 512 threads (8 waves x 16 queries). l = (combo&7) + 8*qt + 256*(combo>>3),
// combo = b*4+ks -> XCD l%8 holds 2 combos' K/V (2 MB < 4 MB L2).
// O_part/m/l stores and Q loads are non-temporal so L2 keeps only K/V.
__global__ __launch_bounds__(512, 4) void attn_kernel(
    const _Float16* __restrict__ qt,     // (B,N,C)
    const _Float16* __restrict__ kt,     // (B,N,C)
    const _Float16* __restrict__ v,      // (B,C,N)
    _Float16* __restrict__ O_part,       // [b][qt32][ks4][q128][c256] f16
    float* __restrict__ m_part,          // [b][qt32][ks4][q128]
    float* __restrict__ l_part) {
    const int l = blockIdx.x;
    const int combo = (l & 7) | ((l >> 8) << 3);
    const int qt_i = (l >> 3) & 31;
    const int b = combo >> 2;
    const int ks = combo & 3;
    const int q0 = qt_i * 128;
    const int tid = threadIdx.x;
    const int w = tid >> 6;              // 0..7
    const int L = tid & 63;
    const int lane15 = L & 15;
    const int quad = L >> 4;

    __shared__ _Float16 Kt_s[TK][260];   // stride 130 dw -> 2-way max (free)
    __shared__ _Float16 Vs[C_][36];      // stride 18 dw  -> 2-way max (free)
    __shared__ _Float16 Ps[8][16][36];
    __shared__ float alpha_s[8][16];

    // Q A-frags: A[m=q][k=c], q = q0 + w*16 + lane15
    halfx8 qfrag[8];
    {
        const _Float16* qrow = qt + ((size_t)b * N_ + q0 + w * 16 + lane15) * C_ + quad * 8;
#pragma unroll
        for (int cs = 0; cs < 8; ++cs)
            qfrag[cs] = __builtin_nontemporal_load((const halfx8*)(qrow + cs * 32));
    }

    floatx4 o_acc[16];
#pragma unroll
    for (int i = 0; i < 16; ++i) o_acc[i] = (floatx4){0.f, 0.f, 0.f, 0.f};
    float m_r[4], l_r[4];
#pragma unroll
    for (int r = 0; r < 4; ++r) { m_r[r] = -1e30f; l_r[r] = 0.f; }

    const _Float16* ktb = kt + (size_t)b * N_ * C_;
    const _Float16* vb  = v  + (size_t)b * C_ * N_;

    const int kbeg = ks * 1024;
    for (int k0 = kbeg; k0 < kbeg + 1024; k0 += TK) {
        // ---- stage K (32 x 256) and V (256 x 32): 1024 chunks each, 512 threads ----
#pragma unroll
        for (int p = 0; p < 2; ++p) {
            int idx = p * 512 + tid;
            int key = idx >> 5;
            int ch  = idx & 31;
            halfx8 val = *(const halfx8*)(ktb + (size_t)(k0 + key) * C_ + ch * 8);
            *(halfx8*)(&Kt_s[key][ch * 8]) = val;
        }
#pragma unroll
        for (int p = 0; p < 2; ++p) {
            int idx = p * 512 + tid;
            int c  = idx >> 2;
            int ch = idx & 3;
            halfx8 val = *(const halfx8*)(vb + (size_t)c * N_ + k0 + ch * 8);
            *(halfx8*)(&Vs[c][ch * 8]) = val;
        }
        __syncthreads();

        // ---- S = Q K^T: row q = quad*4+r, col key = lane15 + 16*ktile ----
        floatx4 s_acc[2];
        s_acc[0] = (floatx4){0.f, 0.f, 0.f, 0.f};
        s_acc[1] = (floatx4){0.f, 0.f, 0.f, 0.f};
#pragma unroll
        for (int ktile = 0; ktile < 2; ++ktile) {
            const _Float16* krow = &Kt_s[ktile * 16 + lane15][quad * 8];
#pragma unroll
            for (int cs = 0; cs < 8; ++cs) {
                halfx8 bf = *(const halfx8*)(krow + cs * 32);
                s_acc[ktile] = __builtin_amdgcn_mfma_f32_16x16x32_f16(qfrag[cs], bf, s_acc[ktile], 0, 0, 0);
            }
        }

        // ---- online softmax (wave-local) ----
        float rmax[4], psum[4], p0[4], p1[4], alpha[4];
#pragma unroll
        for (int r = 0; r < 4; ++r) rmax[r] = fmaxf(s_acc[0][r], s_acc[1][r]);
#pragma unroll
        for (int mask = 1; mask <= 8; mask <<= 1)
#pragma unroll
            for (int r = 0; r < 4; ++r) rmax[r] = fmaxf(rmax[r], __shfl_xor(rmax[r], mask));
#pragma unroll
        for (int r = 0; r < 4; ++r) {
            float mn = fmaxf(m_r[r], rmax[r]);
            alpha[r] = __expf(m_r[r] - mn);
            m_r[r] = mn;
            p0[r] = __expf(s_acc[0][r] - mn);
            p1[r] = __expf(s_acc[1][r] - mn);
            psum[r] = p0[r] + p1[r];
        }
#pragma unroll
        for (int mask = 1; mask <= 8; mask <<= 1)
#pragma unroll
            for (int r = 0; r < 4; ++r) psum[r] += __shfl_xor(psum[r], mask);
#pragma unroll
        for (int r = 0; r < 4; ++r) l_r[r] = l_r[r] * alpha[r] + psum[r];

        // ---- P/alpha -> LDS; wave-local (per-wave DS in-order): no barrier ----
#pragma unroll
        for (int r = 0; r < 4; ++r) {
            Ps[w][quad * 4 + r][lane15]      = (_Float16)p0[r];
            Ps[w][quad * 4 + r][16 + lane15] = (_Float16)p1[r];
        }
        if (lane15 == 0) {
#pragma unroll
            for (int r = 0; r < 4; ++r) alpha_s[w][quad * 4 + r] = alpha[r];
        }

        // ---- O *= alpha; O += V P^T ----
        float av = alpha_s[w][lane15];
#pragma unroll
        for (int i = 0; i < 16; ++i) {
            o_acc[i][0] *= av; o_acc[i][1] *= av; o_acc[i][2] *= av; o_acc[i][3] *= av;
        }
        halfx8 pfrag = *(const halfx8*)(&Ps[w][lane15][quad * 8]);   // B[k=key][n=q]
#pragma unroll
        for (int ct = 0; ct < 16; ++ct) {
            halfx8 vf = *(const halfx8*)(&Vs[ct * 16 + lane15][quad * 8]);  // A[m=c][k=key]
            o_acc[ct] = __builtin_amdgcn_mfma_f32_16x16x32_f16(vf, pfrag, o_acc[ct], 0, 0, 0);
        }
        __syncthreads();   // all waves done reading Kt_s/Vs before restage
    }

    // ---- store partials (non-temporal: keep out of L2) ----
    const size_t pbase = ((size_t)(b * 32 + qt_i)) * 4 + ks;
    _Float16* ob = O_part + (pbase * 128 + (w * 16 + lane15)) * 256;
#pragma unroll
    for (int ct = 0; ct < 16; ++ct) {
        union { _Float16 h[4]; unsigned long long u64; } pk;
#pragma unroll
        for (int r = 0; r < 4; ++r) pk.h[r] = (_Float16)o_acc[ct][r];
        __builtin_nontemporal_store(pk.u64, (unsigned long long*)(ob + ct * 16 + quad * 4));
    }
    if (lane15 == 0) {
        float* mb = m_part + pbase * 128 + w * 16 + quad * 4;
        float* lb = l_part + pbase * 128 + w * 16 + quad * 4;
#pragma unroll
        for (int r = 0; r < 4; ++r) {
            __builtin_nontemporal_store(m_r[r], mb + r);
            __builtin_nontemporal_store(l_r[r], lb + r);
        }
    }
}

// ---------------- combine partials + epilogue (all NT: single-use streams) ----------------
__global__ __launch_bounds__(256) void reduce_kernel(
    const void* __restrict__ x_raw,
    const _Float16* __restrict__ O_part, // [b][qt32][ks4][q128][c256]
    const float* __restrict__ m_part,
    const float* __restrict__ l_part,
    const void* __restrict__ gamma_p,
    void* __restrict__ out,
    const int* __restrict__ flag) {
    const int isf32 = *flag;
    const int b = blockIdx.y;
    const int tid = threadIdx.x;
    const int q = tid & 63;        // lane -> coalesced n
    const int wv = tid >> 6;       // wave -> c range
    const int n = blockIdx.x * 64 + q;
    const int qt_i = n >> 7;
    const int qq = n & 127;

    const size_t sbase = ((size_t)(b * 32 + qt_i)) * 4;
    float m0 = m_part[(sbase + 0) * 128 + qq], m1 = m_part[(sbase + 1) * 128 + qq],
          m2 = m_part[(sbase + 2) * 128 + qq], m3 = m_part[(sbase + 3) * 128 + qq];
    float l0 = l_part[(sbase + 0) * 128 + qq], l1 = l_part[(sbase + 1) * 128 + qq],
          l2 = l_part[(sbase + 2) * 128 + qq], l3 = l_part[(sbase + 3) * 128 + qq];
    float M = fmaxf(fmaxf(m0, m1), fmaxf(m2, m3));
    float w0 = __expf(m0 - M), w1 = __expf(m1 - M), w2 = __expf(m2 - M), w3 = __expf(m3 - M);
    float denom = w0 * l0 + w1 * l1 + w2 * l2 + w3 * l3;
    float g = isf32 ? ((const float*)gamma_p)[0] : bf16_to_f(((const uint16_t*)gamma_p)[0]);
    float s = g / denom;

    const _Float16* o0 = O_part + (sbase * 128 + qq) * 256;
#pragma unroll
    for (int ch = 0; ch < 8; ++ch) {
        const int c0 = wv * 64 + ch * 8;
        halfx8 a     = __builtin_nontemporal_load((const halfx8*)(o0 + c0));
        halfx8 bpart = __builtin_nontemporal_load((const halfx8*)(o0 + 32768 + c0));
        halfx8 cpart = __builtin_nontemporal_load((const halfx8*)(o0 + 65536 + c0));
        halfx8 dpart = __builtin_nontemporal_load((const halfx8*)(o0 + 98304 + c0));
#pragma unroll
        for (int j = 0; j < 8; ++j) {
            float acc = w0 * (float)a[j] + w1 * (float)bpart[j]
                      + w2 * (float)cpart[j] + w3 * (float)dpart[j];
            size_t off = ((size_t)b * 256 + c0 + j) * 4096 + n;
            float xv = isf32 ? __builtin_nontemporal_load((const float*)x_raw + off)
                             : bf16_to_f(((const uint16_t*)x_raw)[off]);
            float val = s * acc + xv;
            if (isf32) __builtin_nontemporal_store(val, (float*)out + off);
            else ((uint16_t*)out)[off] = f_to_bf16(val);
        }
    }
}

// ---------------- fallback: monolithic attn (small ws) ----------------
__global__ __launch_bounds__(256, 2) void attn_full_kernel(
    const void* __restrict__ x_raw,
    const _Float16* __restrict__ qt,
    const _Float16* __restrict__ kt,
    const _Float16* __restrict__ v,
    const void* __restrict__ gamma_p,
    void* __restrict__ out,
    const int* __restrict__ flag) {
    const int isf32 = *flag;
    const int b = blockIdx.y;
    const int q0 = blockIdx.x * 64;
    const int tid = threadIdx.x;
    const int w = tid >> 6;
    const int L = tid & 63;
    const int lane15 = L & 15;
    const int quad = L >> 4;

    __shared__ _Float16 Kt_s[TK][260];
    __shared__ _Float16 Vs[C_][36];
    __shared__ _Float16 Ps[4][16][36];
    __shared__ float alpha_s[4][16];
    __shared__ float l_s[4][16];

    halfx8 qfrag[8];
    {
        const _Float16* qrow = qt + ((size_t)b * N_ + q0 + w * 16 + lane15) * C_ + quad * 8;
#pragma unroll
        for (int cs = 0; cs < 8; ++cs) qfrag[cs] = *(const halfx8*)(qrow + cs * 32);
    }
    floatx4 o_acc[16];
#pragma unroll
    for (int i = 0; i < 16; ++i) o_acc[i] = (floatx4){0.f, 0.f, 0.f, 0.f};
    float m_r[4], l_r[4];
#pragma unroll
    for (int r = 0; r < 4; ++r) { m_r[r] = -1e30f; l_r[r] = 0.f; }
    const _Float16* ktb = kt + (size_t)b * N_ * C_;
    const _Float16* vb  = v  + (size_t)b * C_ * N_;

    for (int k0 = 0; k0 < N_; k0 += TK) {
#pragma unroll
        for (int p = 0; p < 4; ++p) {
            int idx = p * 256 + tid;
            int key = idx >> 5, ch = idx & 31;
            *(halfx8*)(&Kt_s[key][ch * 8]) =
                *(const halfx8*)(ktb + (size_t)(k0 + key) * C_ + ch * 8);
        }
#pragma unroll
        for (int p = 0; p < 4; ++p) {
            int idx = p * 256 + tid;
            int c = idx >> 2, ch = idx & 3;
            *(halfx8*)(&Vs[c][ch * 8]) =
                *(const halfx8*)(vb + (size_t)c * N_ + k0 + ch * 8);
        }
        __syncthreads();
        floatx4 s_acc[2];
        s_acc[0] = (floatx4){0.f, 0.f, 0.f, 0.f};
        s_acc[1] = (floatx4){0.f, 0.f, 0.f, 0.f};
#pragma unroll
        for (int ktile = 0; ktile < 2; ++ktile) {
            const _Float16* krow = &Kt_s[ktile * 16 + lane15][quad * 8];
#pragma unroll
            for (int cs = 0; cs < 8; ++cs) {
                halfx8 bf = *(const halfx8*)(krow + cs * 32);
                s_acc[ktile] = __builtin_amdgcn_mfma_f32_16x16x32_f16(qfrag[cs], bf, s_acc[ktile], 0, 0, 0);
            }
        }
        float rmax[4], psum[4], p0[4], p1[4], alpha[4];
#pragma unroll
        for (int r = 0; r < 4; ++r) rmax[r] = fmaxf(s_acc[0][r], s_acc[1][r]);
#pragma unroll
        for (int mask = 1; mask <= 8; mask <<= 1)
#pragma unroll
            for (int r = 0; r < 4; ++r) rmax[r] = fmaxf(rmax[r], __shfl_xor(rmax[r], mask));
#pragma unroll
        for (int r = 0; r < 4; ++r) {
            float mn = fmaxf(m_r[r], rmax[r]);
            alpha[r] = __expf(m_r[r] - mn);
            m_r[r] = mn;
            p0[r] = __expf(s_acc[0][r] - mn);
            p1[r] = __expf(s_acc[1][r] - mn);
            psum[r] = p0[r] + p1[r];
        }
#pragma unroll
        for (int mask = 1; mask <= 8; mask <<= 1)
#pragma unroll
            for (int r = 0; r < 4; ++r) psum[r] += __shfl_xor(psum[r], mask);
#pragma unroll
        for (int r = 0; r < 4; ++r) l_r[r] = l_r[r] * alpha[r] + psum[r];
#pragma unroll
        for (int r = 0; r < 4; ++r) {
            Ps[w][quad * 4 + r][lane15]      = (_Float16)p0[r];
            Ps[w][quad * 4 + r][16 + lane15] = (_Float16)p1[r];
        }
        if (lane15 == 0) {
#pragma unroll
            for (int r = 0; r < 4; ++r) alpha_s[w][quad * 4 + r] = alpha[r];
        }
        __syncthreads();
        float av = alpha_s[w][lane15];
#pragma unroll
        for (int i = 0; i < 16; ++i) {
            o_acc[i][0] *= av; o_acc[i][1] *= av; o_acc[i][2] *= av; o_acc[i][3] *= av;
        }
        halfx8 pfrag = *(const halfx8*)(&Ps[w][lane15][quad * 8]);
#pragma unroll
        for (int ct = 0; ct < 16; ++ct) {
            halfx8 vf = *(const halfx8*)(&Vs[ct * 16 + lane15][quad * 8]);
            o_acc[ct] = __builtin_amdgcn_mfma_f32_16x16x32_f16(vf, pfrag, o_acc[ct], 0, 0, 0);
        }
        __syncthreads();
    }
    if (lane15 == 0) {
#pragma unroll
        for (int r = 0; r < 4; ++r) l_s[w][quad * 4 + r] = l_r[r];
    }
    __syncthreads();
    float linv = 1.0f / l_s[w][lane15];
    float g = isf32 ? ((const float*)gamma_p)[0] : bf16_to_f(((const uint16_t*)gamma_p)[0]);
    const int n_out = q0 + w * 16 + lane15;
#pragma unroll
    for (int ct = 0; ct < 16; ++ct)
#pragma unroll
        for (int r = 0; r < 4; ++r) {
            int c = ct * 16 + quad * 4 + r;
            size_t off = ((size_t)b * C_ + c) * N_ + n_out;
            float val = g * o_acc[ct][r] * linv +
                        (isf32 ? ((const float*)x_raw)[off] : bf16_to_f(((const uint16_t*)x_raw)[off]));
            if (isf32) ((float*)out)[off] = val;
            else ((uint16_t*)out)[off] = f_to_bf16(val);
        }
}

// ---------------- launcher ----------------
extern "C" void kernel_launch(void* const* d_in, const int* in_sizes, int n_in,
                              void* d_out, int out_size, void* d_ws, size_t ws_size,
                              hipStream_t stream) {
    const void* x  = d_in[0];
    const void* wq = d_in[1];
    const void* wk = d_in[2];
    const void* wv = d_in[3];
    const void* gm = d_in[4];

    char* ws = (char*)d_ws;
    int* flag    = (int*)ws;
    _Float16* wf = (_Float16*)(ws + 4096);
    size_t o0 = 4096 + 393216;
    _Float16* qt = (_Float16*)(ws + o0);
    _Float16* kt = (_Float16*)(ws + o0 + 8388608);
    _Float16* v  = (_Float16*)(ws + o0 + 2 * 8388608);
    size_t o1 = o0 + 3 * 8388608;                       // 25,563,136
    _Float16* opart = (_Float16*)(ws + o1);             // 33,554,432 B
    float* mpart = (float*)(ws + o1 + 33554432);        // 262,144 B
    float* lpart = (float*)(ws + o1 + 33554432 + 262144);
    const size_t need = o1 + 33554432 + 2 * 262144;     // ~59.6 MB

    sniff_kernel<<<dim3(1), dim3(256), 0, stream>>>((const uint16_t*)wq, flag);
    wconv_kernel<<<dim3(768), dim3(256), 0, stream>>>(wq, wk, wv, wf, flag);
    proj_kernel<<<dim3(64, 4, 3), dim3(256), 0, stream>>>(x, wf, qt, kt, v, flag);
    if (ws_size >= need) {
        attn_kernel<<<dim3(512), dim3(512), 0, stream>>>(qt, kt, v, opart, mpart, lpart);
        reduce_kernel<<<dim3(64, 4), dim3(256), 0, stream>>>(x, opart, mpart, lpart, gm, d_out, flag);
    } else {
        attn_full_kernel<<<dim3(64, 4), dim3(256), 0, stream>>>(x, qt, kt, v, gm, d_out, flag);
    }
}

// Round 7
// 535.054 us; speedup vs baseline: 1.5175x; 1.0603x over previous
//
#include <hip/hip_runtime.h>
#include <stdint.h>

#define B_ 4
#define C_ 256
#define N_ 4096
#define TK 32

using floatx4 = __attribute__((ext_vector_type(4))) float;
using halfx8  = __attribute__((ext_vector_type(8))) _Float16;

__device__ __forceinline__ float bf16_to_f(uint16_t u) {
    union { uint32_t u; float f; } c; c.u = ((uint32_t)u) << 16; return c.f;
}
__device__ __forceinline__ uint16_t f_to_bf16(float f) {
    union { float f; uint32_t u; } c; c.f = f;
    uint32_t u = c.u;
    u += 0x7FFFu + ((u >> 16) & 1u);   // RNE
    return (uint16_t)(u >> 16);
}

// ---------------- sniff input dtype (1 = f32, 0 = bf16) ----------------
__global__ void sniff_kernel(const uint16_t* __restrict__ wq_u16, int* __restrict__ flag) {
    __shared__ int cnt;
    if (threadIdx.x == 0) cnt = 0;
    __syncthreads();
    int local = 0;
    for (int i = threadIdx.x; i < 8192; i += 256) {
        int e = (wq_u16[i] >> 7) & 0xFF;
        if (e >= 132) local++;
    }
    atomicAdd(&cnt, local);
    __syncthreads();
    if (threadIdx.x == 0) *flag = (cnt > 64) ? 1 : 0;
}

// ---------------- W -> f16 ----------------
__global__ void wconv_kernel(const void* __restrict__ wq,
                             const void* __restrict__ wk,
                             const void* __restrict__ wv,
                             _Float16* __restrict__ wf,
                             const int* __restrict__ flag) {
    const int isf32 = *flag;
    int idx = blockIdx.x * 256 + threadIdx.x;
    int mat = idx >> 16;
    int off = idx & 65535;
    const void* src = (mat == 0) ? wq : ((mat == 1) ? wk : wv);
    float v = isf32 ? ((const float*)src)[off] : bf16_to_f(((const uint16_t*)src)[off]);
    wf[idx] = (_Float16)v;
}

// ---------------- QKV projection (MFMA f16), mat = blockIdx.z ----------------
__global__ __launch_bounds__(256) void proj_kernel(
    const void* __restrict__ x_raw,      // (B,C,N) bf16 or f32
    const _Float16* __restrict__ wf,     // 3 x (C,C) f16
    _Float16* __restrict__ qt,           // (B,N,C)
    _Float16* __restrict__ kt,           // (B,N,C)
    _Float16* __restrict__ v,            // (B,C,N)
    const int* __restrict__ flag) {
    const int isf32 = *flag;
    const int b = blockIdx.y;
    const int mat = blockIdx.z;
    const int n0 = blockIdx.x * 64;
    const int tid = threadIdx.x;
    const int w = tid >> 6;
    const int L = tid & 63;
    const int lane15 = L & 15;
    const int quad = L >> 4;
    const int n = n0 + w * 16 + lane15;

    halfx8 bfrag[8];
    const size_t xbase = (size_t)b * C_ * N_;
    if (isf32) {
        const float* xb = (const float*)x_raw + xbase;
#pragma unroll
        for (int cs = 0; cs < 8; ++cs) {
            const int cbase = cs * 32 + quad * 8;
            halfx8 f;
#pragma unroll
            for (int j = 0; j < 8; ++j)
                f[j] = (_Float16)xb[(size_t)(cbase + j) * N_ + n];
            bfrag[cs] = f;
        }
    } else {
        const uint16_t* xb = (const uint16_t*)x_raw + xbase;
#pragma unroll
        for (int cs = 0; cs < 8; ++cs) {
            const int cbase = cs * 32 + quad * 8;
            halfx8 f;
#pragma unroll
            for (int j = 0; j < 8; ++j)
                f[j] = (_Float16)bf16_to_f(xb[(size_t)(cbase + j) * N_ + n]);
            bfrag[cs] = f;
        }
    }

    const _Float16* wm = wf + mat * (C_ * C_);
#pragma unroll 4
    for (int ot = 0; ot < 16; ++ot) {
        const int obase = ot * 16;
        floatx4 acc = {0.f, 0.f, 0.f, 0.f};
        const _Float16* wrow = wm + (size_t)(obase + lane15) * C_ + quad * 8;
#pragma unroll
        for (int cs = 0; cs < 8; ++cs) {
            halfx8 af = *(const halfx8*)(wrow + cs * 32);
            acc = __builtin_amdgcn_mfma_f32_16x16x32_f16(af, bfrag[cs], acc, 0, 0, 0);
        }
        if (mat < 2) {
            _Float16* dst = (mat == 0 ? qt : kt) +
                            ((size_t)b * N_ + n) * C_ + obase + quad * 4;
            union { _Float16 h[4]; unsigned long long u64; } pk;
#pragma unroll
            for (int r = 0; r < 4; ++r) pk.h[r] = (_Float16)acc[r];
            *(unsigned long long*)dst = pk.u64;
        } else {
            _Float16* dst = v + ((size_t)b * C_ + obase + quad * 4) * N_ + n;
#pragma unroll
            for (int r = 0; r < 4; ++r) dst[(size_t)r * N_] = (_Float16)acc[r];
        }
    }
}

// ---------------- flash attention: Qtile=256 (1024 thr, 16 waves), ks=4 ----------------
// Minimal delta from the proven Qtile=128 kernel: only tile constants changed.
// Separate __shared__ arrays, per-lane NT O_part stores (round-5-proven pattern).
// Grid 256, swizzle: l = (combo&7) + 8*qt + 128*(combo>>3), combo = b*4+ks.
__global__ __launch_bounds__(1024) void attn_kernel(
    const _Float16* __restrict__ qt,     // (B,N,C)
    const _Float16* __restrict__ kt,     // (B,N,C)
    const _Float16* __restrict__ v,      // (B,C,N)
    _Float16* __restrict__ O_part,       // [b][qt16][ks4][q256][c256] f16
    float* __restrict__ m_part,          // [b][qt16][ks4][q256]
    float* __restrict__ l_part) {
    const int l = blockIdx.x;
    const int combo = (l & 7) | ((l >> 7) << 3);
    const int qt_i = (l >> 3) & 15;
    const int b = combo >> 2;
    const int ks = combo & 3;
    const int q0 = qt_i * 256;
    const int tid = threadIdx.x;
    const int w = tid >> 6;              // 0..15
    const int L = tid & 63;
    const int lane15 = L & 15;
    const int quad = L >> 4;

    __shared__ _Float16 Kt_s[TK][260];   // stride 130 dw -> 2-way max (free)
    __shared__ _Float16 Vs[C_][36];      // stride 18 dw  -> 2-way max (free)
    __shared__ _Float16 Ps[16][16][36];
    __shared__ float alpha_s[16][16];

    // Q A-frags: A[m=q][k=c], q = q0 + w*16 + lane15
    halfx8 qfrag[8];
    {
        const _Float16* qrow = qt + ((size_t)b * N_ + q0 + w * 16 + lane15) * C_ + quad * 8;
#pragma unroll
        for (int cs = 0; cs < 8; ++cs)
            qfrag[cs] = __builtin_nontemporal_load((const halfx8*)(qrow + cs * 32));
    }

    floatx4 o_acc[16];
#pragma unroll
    for (int i = 0; i < 16; ++i) o_acc[i] = (floatx4){0.f, 0.f, 0.f, 0.f};
    float m_r[4], l_r[4];
#pragma unroll
    for (int r = 0; r < 4; ++r) { m_r[r] = -1e30f; l_r[r] = 0.f; }

    const _Float16* ktb = kt + (size_t)b * N_ * C_;
    const _Float16* vb  = v  + (size_t)b * C_ * N_;

    const int kbeg = ks * 1024;
    for (int k0 = kbeg; k0 < kbeg + 1024; k0 += TK) {
        // ---- stage K (32x256) + V (256x32): exactly one 16 B chunk per thread ----
        {
            int key = tid >> 5, ch = tid & 31;
            *(halfx8*)(&Kt_s[key][ch * 8]) =
                *(const halfx8*)(ktb + (size_t)(k0 + key) * C_ + ch * 8);
            int c = tid >> 2, ch2 = tid & 3;
            *(halfx8*)(&Vs[c][ch2 * 8]) =
                *(const halfx8*)(vb + (size_t)c * N_ + k0 + ch2 * 8);
        }
        __syncthreads();

        // ---- S = Q K^T: row q = quad*4+r, col key = lane15 + 16*ktile ----
        floatx4 s_acc[2];
        s_acc[0] = (floatx4){0.f, 0.f, 0.f, 0.f};
        s_acc[1] = (floatx4){0.f, 0.f, 0.f, 0.f};
#pragma unroll
        for (int ktile = 0; ktile < 2; ++ktile) {
            const _Float16* krow = &Kt_s[ktile * 16 + lane15][quad * 8];
#pragma unroll
            for (int cs = 0; cs < 8; ++cs) {
                halfx8 bf = *(const halfx8*)(krow + cs * 32);
                s_acc[ktile] = __builtin_amdgcn_mfma_f32_16x16x32_f16(qfrag[cs], bf, s_acc[ktile], 0, 0, 0);
            }
        }

        // ---- online softmax (wave-local) ----
        float rmax[4], psum[4], p0[4], p1[4], alpha[4];
#pragma unroll
        for (int r = 0; r < 4; ++r) rmax[r] = fmaxf(s_acc[0][r], s_acc[1][r]);
#pragma unroll
        for (int mask = 1; mask <= 8; mask <<= 1)
#pragma unroll
            for (int r = 0; r < 4; ++r) rmax[r] = fmaxf(rmax[r], __shfl_xor(rmax[r], mask));
#pragma unroll
        for (int r = 0; r < 4; ++r) {
            float mn = fmaxf(m_r[r], rmax[r]);
            alpha[r] = __expf(m_r[r] - mn);
            m_r[r] = mn;
            p0[r] = __expf(s_acc[0][r] - mn);
            p1[r] = __expf(s_acc[1][r] - mn);
            psum[r] = p0[r] + p1[r];
        }
#pragma unroll
        for (int mask = 1; mask <= 8; mask <<= 1)
#pragma unroll
            for (int r = 0; r < 4; ++r) psum[r] += __shfl_xor(psum[r], mask);
#pragma unroll
        for (int r = 0; r < 4; ++r) l_r[r] = l_r[r] * alpha[r] + psum[r];

        // ---- P/alpha -> LDS; wave-local (per-wave DS in-order): no barrier ----
#pragma unroll
        for (int r = 0; r < 4; ++r) {
            Ps[w][quad * 4 + r][lane15]      = (_Float16)p0[r];
            Ps[w][quad * 4 + r][16 + lane15] = (_Float16)p1[r];
        }
        if (lane15 == 0) {
#pragma unroll
            for (int r = 0; r < 4; ++r) alpha_s[w][quad * 4 + r] = alpha[r];
        }

        // ---- O *= alpha; O += V P^T ----
        float av = alpha_s[w][lane15];
#pragma unroll
        for (int i = 0; i < 16; ++i) {
            o_acc[i][0] *= av; o_acc[i][1] *= av; o_acc[i][2] *= av; o_acc[i][3] *= av;
        }
        halfx8 pfrag = *(const halfx8*)(&Ps[w][lane15][quad * 8]);   // B[k=key][n=q]
#pragma unroll
        for (int ct = 0; ct < 16; ++ct) {
            halfx8 vf = *(const halfx8*)(&Vs[ct * 16 + lane15][quad * 8]);  // A[m=c][k=key]
            o_acc[ct] = __builtin_amdgcn_mfma_f32_16x16x32_f16(vf, pfrag, o_acc[ct], 0, 0, 0);
        }
        __syncthreads();   // all waves done reading Kt_s/Vs before restage
    }

    // ---- store partials (round-5-proven per-lane NT stores) ----
    const size_t pbase = (size_t)((b * 16 + qt_i) * 4 + ks);
    _Float16* ob = O_part + (pbase * 256 + (size_t)(w * 16 + lane15)) * 256;
#pragma unroll
    for (int ct = 0; ct < 16; ++ct) {
        union { _Float16 h[4]; unsigned long long u64; } pk;
#pragma unroll
        for (int r = 0; r < 4; ++r) pk.h[r] = (_Float16)o_acc[ct][r];
        __builtin_nontemporal_store(pk.u64, (unsigned long long*)(ob + ct * 16 + quad * 4));
    }
    if (lane15 == 0) {
        float* mb = m_part + pbase * 256 + w * 16 + quad * 4;
        float* lb = l_part + pbase * 256 + w * 16 + quad * 4;
#pragma unroll
        for (int r = 0; r < 4; ++r) {
            __builtin_nontemporal_store(m_r[r], mb + r);
            __builtin_nontemporal_store(l_r[r], lb + r);
        }
    }
}

// ---------------- combine partials + epilogue (round-5-proven shape, 256-q strides) ----
__global__ __launch_bounds__(256) void reduce_kernel(
    const void* __restrict__ x_raw,
    const _Float16* __restrict__ O_part, // [b][qt16][ks4][q256][c256]
    const float* __restrict__ m_part,
    const float* __restrict__ l_part,
    const void* __restrict__ gamma_p,
    void* __restrict__ out,
    const int* __restrict__ flag) {
    const int isf32 = *flag;
    const int b = blockIdx.y;
    const int tid = threadIdx.x;
    const int q = tid & 63;        // lane -> coalesced n
    const int wv = tid >> 6;       // wave -> c range
    const int n = blockIdx.x * 64 + q;
    const int qt_i = n >> 8;
    const int qq = n & 255;

    const size_t sbase = (size_t)(b * 16 + qt_i) * 4;
    float m0 = m_part[(sbase + 0) * 256 + qq], m1 = m_part[(sbase + 1) * 256 + qq],
          m2 = m_part[(sbase + 2) * 256 + qq], m3 = m_part[(sbase + 3) * 256 + qq];
    float l0 = l_part[(sbase + 0) * 256 + qq], l1 = l_part[(sbase + 1) * 256 + qq],
          l2 = l_part[(sbase + 2) * 256 + qq], l3 = l_part[(sbase + 3) * 256 + qq];
    float M = fmaxf(fmaxf(m0, m1), fmaxf(m2, m3));
    float w0 = __expf(m0 - M), w1 = __expf(m1 - M), w2 = __expf(m2 - M), w3 = __expf(m3 - M);
    float denom = w0 * l0 + w1 * l1 + w2 * l2 + w3 * l3;
    float g = isf32 ? ((const float*)gamma_p)[0] : bf16_to_f(((const uint16_t*)gamma_p)[0]);
    float s = g / denom;

    const _Float16* o0 = O_part + sbase * 65536 + (size_t)qq * 256;
#pragma unroll
    for (int ch = 0; ch < 8; ++ch) {
        const int c0 = wv * 64 + ch * 8;
        halfx8 a     = __builtin_nontemporal_load((const halfx8*)(o0 + c0));
        halfx8 bpart = __builtin_nontemporal_load((const halfx8*)(o0 + 65536 + c0));
        halfx8 cpart = __builtin_nontemporal_load((const halfx8*)(o0 + 131072 + c0));
        halfx8 dpart = __builtin_nontemporal_load((const halfx8*)(o0 + 196608 + c0));
#pragma unroll
        for (int j = 0; j < 8; ++j) {
            float acc = w0 * (float)a[j] + w1 * (float)bpart[j]
                      + w2 * (float)cpart[j] + w3 * (float)dpart[j];
            size_t off = ((size_t)b * 256 + c0 + j) * 4096 + n;
            float xv = isf32 ? __builtin_nontemporal_load((const float*)x_raw + off)
                             : bf16_to_f(((const uint16_t*)x_raw)[off]);
            float val = s * acc + xv;
            if (isf32) __builtin_nontemporal_store(val, (float*)out + off);
            else ((uint16_t*)out)[off] = f_to_bf16(val);
        }
    }
}

// ---------------- fallback: monolithic attn (small ws) ----------------
__global__ __launch_bounds__(256, 2) void attn_full_kernel(
    const void* __restrict__ x_raw,
    const _Float16* __restrict__ qt,
    const _Float16* __restrict__ kt,
    const _Float16* __restrict__ v,
    const void* __restrict__ gamma_p,
    void* __restrict__ out,
    const int* __restrict__ flag) {
    const int isf32 = *flag;
    const int b = blockIdx.y;
    const int q0 = blockIdx.x * 64;
    const int tid = threadIdx.x;
    const int w = tid >> 6;
    const int L = tid & 63;
    const int lane15 = L & 15;
    const int quad = L >> 4;

    __shared__ _Float16 Kt_s[TK][260];
    __shared__ _Float16 Vs[C_][36];
    __shared__ _Float16 Ps[4][16][36];
    __shared__ float alpha_s[4][16];
    __shared__ float l_s[4][16];

    halfx8 qfrag[8];
    {
        const _Float16* qrow = qt + ((size_t)b * N_ + q0 + w * 16 + lane15) * C_ + quad * 8;
#pragma unroll
        for (int cs = 0; cs < 8; ++cs) qfrag[cs] = *(const halfx8*)(qrow + cs * 32);
    }
    floatx4 o_acc[16];
#pragma unroll
    for (int i = 0; i < 16; ++i) o_acc[i] = (floatx4){0.f, 0.f, 0.f, 0.f};
    float m_r[4], l_r[4];
#pragma unroll
    for (int r = 0; r < 4; ++r) { m_r[r] = -1e30f; l_r[r] = 0.f; }
    const _Float16* ktb = kt + (size_t)b * N_ * C_;
    const _Float16* vb  = v  + (size_t)b * C_ * N_;

    for (int k0 = 0; k0 < N_; k0 += TK) {
#pragma unroll
        for (int p = 0; p < 4; ++p) {
            int idx = p * 256 + tid;
            int key = idx >> 5, ch = idx & 31;
            *(halfx8*)(&Kt_s[key][ch * 8]) =
                *(const halfx8*)(ktb + (size_t)(k0 + key) * C_ + ch * 8);
        }
#pragma unroll
        for (int p = 0; p < 4; ++p) {
            int idx = p * 256 + tid;
            int c = idx >> 2, ch = idx & 3;
            *(halfx8*)(&Vs[c][ch * 8]) =
                *(const halfx8*)(vb + (size_t)c * N_ + k0 + ch * 8);
        }
        __syncthreads();
        floatx4 s_acc[2];
        s_acc[0] = (floatx4){0.f, 0.f, 0.f, 0.f};
        s_acc[1] = (floatx4){0.f, 0.f, 0.f, 0.f};
#pragma unroll
        for (int ktile = 0; ktile < 2; ++ktile) {
            const _Float16* krow = &Kt_s[ktile * 16 + lane15][quad * 8];
#pragma unroll
            for (int cs = 0; cs < 8; ++cs) {
                halfx8 bf = *(const halfx8*)(krow + cs * 32);
                s_acc[ktile] = __builtin_amdgcn_mfma_f32_16x16x32_f16(qfrag[cs], bf, s_acc[ktile], 0, 0, 0);
            }
        }
        float rmax[4], psum[4], p0[4], p1[4], alpha[4];
#pragma unroll
        for (int r = 0; r < 4; ++r) rmax[r] = fmaxf(s_acc[0][r], s_acc[1][r]);
#pragma unroll
        for (int mask = 1; mask <= 8; mask <<= 1)
#pragma unroll
            for (int r = 0; r < 4; ++r) rmax[r] = fmaxf(rmax[r], __shfl_xor(rmax[r], mask));
#pragma unroll
        for (int r = 0; r < 4; ++r) {
            float mn = fmaxf(m_r[r], rmax[r]);
            alpha[r] = __expf(m_r[r] - mn);
            m_r[r] = mn;
            p0[r] = __expf(s_acc[0][r] - mn);
            p1[r] = __expf(s_acc[1][r] - mn);
            psum[r] = p0[r] + p1[r];
        }
#pragma unroll
        for (int mask = 1; mask <= 8; mask <<= 1)
#pragma unroll
            for (int r = 0; r < 4; ++r) psum[r] += __shfl_xor(psum[r], mask);
#pragma unroll
        for (int r = 0; r < 4; ++r) l_r[r] = l_r[r] * alpha[r] + psum[r];
#pragma unroll
        for (int r = 0; r < 4; ++r) {
            Ps[w][quad * 4 + r][lane15]      = (_Float16)p0[r];
            Ps[w][quad * 4 + r][16 + lane15] = (_Float16)p1[r];
        }
        if (lane15 == 0) {
#pragma unroll
            for (int r = 0; r < 4; ++r) alpha_s[w][quad * 4 + r] = alpha[r];
        }
        __syncthreads();
        float av = alpha_s[w][lane15];
#pragma unroll
        for (int i = 0; i < 16; ++i) {
            o_acc[i][0] *= av; o_acc[i][1] *= av; o_acc[i][2] *= av; o_acc[i][3] *= av;
        }
        halfx8 pfrag = *(const halfx8*)(&Ps[w][lane15][quad * 8]);
#pragma unroll
        for (int ct = 0; ct < 16; ++ct) {
            halfx8 vf = *(const halfx8*)(&Vs[ct * 16 + lane15][quad * 8]);
            o_acc[ct] = __builtin_amdgcn_mfma_f32_16x16x32_f16(vf, pfrag, o_acc[ct], 0, 0, 0);
        }
        __syncthreads();
    }
    if (lane15 == 0) {
#pragma unroll
        for (int r = 0; r < 4; ++r) l_s[w][quad * 4 + r] = l_r[r];
    }
    __syncthreads();
    float linv = 1.0f / l_s[w][lane15];
    float g = isf32 ? ((const float*)gamma_p)[0] : bf16_to_f(((const uint16_t*)gamma_p)[0]);
    const int n_out = q0 + w * 16 + lane15;
#pragma unroll
    for (int ct = 0; ct < 16; ++ct)
#pragma unroll
        for (int r = 0; r < 4; ++r) {
            int c = ct * 16 + quad * 4 + r;
            size_t off = ((size_t)b * C_ + c) * N_ + n_out;
            float val = g * o_acc[ct][r] * linv +
                        (isf32 ? ((const float*)x_raw)[off] : bf16_to_f(((const uint16_t*)x_raw)[off]));
            if (isf32) ((float*)out)[off] = val;
            else ((uint16_t*)out)[off] = f_to_bf16(val);
        }
}

// ---------------- launcher ----------------
extern "C" void kernel_launch(void* const* d_in, const int* in_sizes, int n_in,
                              void* d_out, int out_size, void* d_ws, size_t ws_size,
                              hipStream_t stream) {
    const void* x  = d_in[0];
    const void* wq = d_in[1];
    const void* wk = d_in[2];
    const void* wv = d_in[3];
    const void* gm = d_in[4];

    char* ws = (char*)d_ws;
    int* flag    = (int*)ws;
    _Float16* wf = (_Float16*)(ws + 4096);
    size_t o0 = 4096 + 393216;
    _Float16* qt = (_Float16*)(ws + o0);
    _Float16* kt = (_Float16*)(ws + o0 + 8388608);
    _Float16* v  = (_Float16*)(ws + o0 + 2 * 8388608);
    size_t o1 = o0 + 3 * 8388608;                       // 25,563,136
    _Float16* opart = (_Float16*)(ws + o1);             // 33,554,432 B
    float* mpart = (float*)(ws + o1 + 33554432);        // 262,144 B
    float* lpart = (float*)(ws + o1 + 33554432 + 262144);
    const size_t need = o1 + 33554432 + 2 * 262144;     // ~59.6 MB

    sniff_kernel<<<dim3(1), dim3(256), 0, stream>>>((const uint16_t*)wq, flag);
    wconv_kernel<<<dim3(768), dim3(256), 0, stream>>>(wq, wk, wv, wf, flag);
    proj_kernel<<<dim3(64, 4, 3), dim3(256), 0, stream>>>(x, wf, qt, kt, v, flag);
    if (ws_size >= need) {
        attn_kernel<<<dim3(256), dim3(1024), 0, stream>>>(qt, kt, v, opart, mpart, lpart);
        reduce_kernel<<<dim3(64, 4), dim3(256), 0, stream>>>(x, opart, mpart, lpart, gm, d_out, flag);
    } else {
        attn_full_kernel<<<dim3(64, 4), dim3(256), 0, stream>>>(x, qt, kt, v, gm, d_out, flag);
    }
}